// Round 2
// baseline (263.522 us; speedup 1.0000x reference)
//
#include <hip/hip_runtime.h>

// B=8192, L=512, P=64, S=32, O=200
// Outputs (flat): [min1, min2, sub_min1, sub_min2, out(8192x200)]

#define NL 512
#define NP 64
#define NS 32
#define NO 200
#define NB 8192

// ws layout (4-byte units)
#define WS_SUM    0      // float: sum of per-sample dmin
#define WS_COLMIN 1      // uint[64]  encoded-float atomicMin
#define WS_SUBMIN 65     // uint[2048]
#define WS_GRPSUM 2113   // float[64]
#define WS_COUNT  2177   // uint[64]
#define WS_SP2    2305   // float[2048] sub-proto sq-norms
#define WS_SS     4360   // float[8192] ||x_b||^2
#define WS_IDX    12560  // int[8192]

__device__ __forceinline__ unsigned encf(float f) {
  unsigned u = __float_as_uint(f);
  return (u & 0x80000000u) ? ~u : (u | 0x80000000u);
}
__device__ __forceinline__ float decf(unsigned m) {
  return __uint_as_float((m & 0x80000000u) ? (m ^ 0x80000000u) : ~m);
}
__device__ __forceinline__ float wred(float v) {
#pragma unroll
  for (int m = 32; m >= 1; m >>= 1) v += __shfl_xor(v, m, 64);
  return v;
}
__device__ __forceinline__ float dot4(const float4& a, const float4& b) {
  return a.x * b.x + a.y * b.y + a.z * b.z + a.w * b.w;
}
__device__ __forceinline__ float dot8(const float4& a0, const float4& a1,
                                      const float4& b0, const float4& b1) {
  return dot4(a0, b0) + dot4(a1, b1);
}

// blocks 0..511: sub-proto sq-norms (4 rows/block, 1 wave each). block 512: init.
__global__ __launch_bounds__(256) void hier_prep(const float* __restrict__ subp,
                                                 float* __restrict__ ws) {
  if (blockIdx.x == 512) {
    unsigned* wsu = (unsigned*)ws;
    int t = threadIdx.x;
    if (t == 0) ws[WS_SUM] = 0.f;
    if (t < 64) {
      wsu[WS_COLMIN + t] = 0xFFFFFFFFu;
      ws[WS_GRPSUM + t] = 0.f;
      wsu[WS_COUNT + t] = 0u;
    }
    for (int u = t; u < NP * NS; u += 256) wsu[WS_SUBMIN + u] = 0xFFFFFFFFu;
    return;
  }
  const int lane = threadIdx.x & 63;
  const int row = blockIdx.x * 4 + (threadIdx.x >> 6);  // 0..2047
  const float4* rv = (const float4*)(subp + (size_t)row * NL);
  float4 a = rv[2 * lane], b = rv[2 * lane + 1];
  float s = wred(dot8(a, b, a, b));
  if (lane == 0) ws[WS_SP2 + row] = s;
}

// 256 blocks x 256 threads: block = 32 samples x 64 protos GEMM + stats.
// Thread tile 2x4: ri = tid>>4 (rows 2ri,2ri+1), ci = tid&15 (cols 4ci..+3).
__global__ __launch_bounds__(256) void hier_phase1(const float* __restrict__ x,
                                                   const float* __restrict__ proto,
                                                   float* __restrict__ ws) {
  __shared__ float4 xs4[32 * 16];   // [row][chunk^((row>>1)&15)]
  __shared__ float4 ps4[64 * 16];   // [row][chunk^(row>>2)]
  __shared__ float ss_l[32], pp_l[64];
  __shared__ float part[256];
  __shared__ unsigned colmin_l[64];
  __shared__ float rowmin_l[32];
  __shared__ int rowarg_l[32];

  const int tid = threadIdx.x;
  const int b0 = blockIdx.x * 32;
  const int ri = tid >> 4;
  const int ci = tid & 15;

  // ||x||^2 per row: 8 threads per row, 16 float4 each
  {
    int s = tid >> 3, q = tid & 7;
    const float4* xv = (const float4*)(x + (size_t)(b0 + s) * NL) + q * 16;
    float a = 0;
#pragma unroll
    for (int j = 0; j < 16; ++j) a += dot4(xv[j], xv[j]);
    part[tid] = a;
  }
  __syncthreads();
  if (tid < 32) {
    float v = 0;
#pragma unroll
    for (int q = 0; q < 8; ++q) v += part[tid * 8 + q];
    ss_l[tid] = v;
    ws[WS_SS + b0 + tid] = v;
  }
  __syncthreads();
  // ||proto||^2 per row: 4 threads per row, 32 float4 each
  {
    int c = tid >> 2, h = tid & 3;
    const float4* pv = (const float4*)(proto + (size_t)c * NL) + h * 32;
    float a = 0;
#pragma unroll
    for (int j = 0; j < 32; ++j) a += dot4(pv[j], pv[j]);
    part[tid] = a;
  }
  __syncthreads();
  if (tid < 64) {
    pp_l[tid] = part[tid * 4] + part[tid * 4 + 1] + part[tid * 4 + 2] + part[tid * 4 + 3];
    colmin_l[tid] = 0xFFFFFFFFu;
  }

  float acc[2][4] = {{0.f, 0.f, 0.f, 0.f}, {0.f, 0.f, 0.f, 0.f}};

  for (int kt = 0; kt < 8; ++kt) {
    __syncthreads();
    // stage x tile: 512 float4 chunks, 2 per thread (coalesced)
#pragma unroll
    for (int v = 0; v < 2; ++v) {
      int f = v * 256 + tid;
      int s = f >> 4, kk = f & 15;
      xs4[s * 16 + (kk ^ ((s >> 1) & 15))] =
          ((const float4*)(x + (size_t)(b0 + s) * NL + kt * 64))[kk];
    }
    // stage proto tile: 1024 chunks, 4 per thread
#pragma unroll
    for (int v = 0; v < 4; ++v) {
      int f = v * 256 + tid;
      int c = f >> 4, kk = f & 15;
      ps4[c * 16 + (kk ^ (c >> 2))] =
          ((const float4*)(proto + (size_t)c * NL + kt * 64))[kk];
    }
    __syncthreads();
#pragma unroll
    for (int kk = 0; kk < 16; ++kk) {
      float4 a0 = xs4[(2 * ri) * 16 + (kk ^ (ri & 15))];
      float4 a1 = xs4[(2 * ri + 1) * 16 + (kk ^ (ri & 15))];
#pragma unroll
      for (int j = 0; j < 4; ++j) {
        float4 b = ps4[(4 * ci + j) * 16 + (kk ^ ci)];
        acc[0][j] += dot4(a0, b);
        acc[1][j] += dot4(a1, b);
      }
    }
  }
  __syncthreads();

  // stats: d[i][j] = ss + pp - 2*acc
#pragma unroll
  for (int i = 0; i < 2; ++i) {
    const int r = 2 * ri + i;
    float rmin = 1e30f;
    int rarg = 0;
    float dv[4];
#pragma unroll
    for (int j = 0; j < 4; ++j) {
      dv[j] = ss_l[r] + pp_l[4 * ci + j] - 2.f * acc[i][j];
      if (dv[j] < rmin) { rmin = dv[j]; rarg = 4 * ci + j; }
    }
    if (i == 1) {
#pragma unroll
      for (int j = 0; j < 4; ++j)
        atomicMin(&colmin_l[4 * ci + j], encf(fminf(dv[j], ss_l[r - 1] + pp_l[4 * ci + j] - 2.f * acc[0][j])));
    }
    // reduce (min,arg) across the 16 ci lanes (first-index tie-break)
#pragma unroll
    for (int m = 1; m <= 8; m <<= 1) {
      float om = __shfl_xor(rmin, m, 64);
      int oa = __shfl_xor(rarg, m, 64);
      if (om < rmin || (om == rmin && oa < rarg)) { rmin = om; rarg = oa; }
    }
    if (ci == 0) { rowmin_l[r] = rmin; rowarg_l[r] = rarg; }
  }
  __syncthreads();

  if (tid < 64) atomicMin((unsigned*)ws + WS_COLMIN + tid, colmin_l[tid]);
  if (tid < 32) ((int*)ws)[WS_IDX + b0 + tid] = rowarg_l[tid];
  if (tid < 32) {
    float v = rowmin_l[tid];
#pragma unroll
    for (int m = 16; m >= 1; m >>= 1) v += __shfl_xor(v, m, 64);
    if (tid == 0) atomicAdd(&ws[WS_SUM], v);
  }
}

// 2048 blocks x 256 threads: 1 wave per sample. lane = s_lo*8 + c.
__global__ __launch_bounds__(256) void hier_phase2(const float* __restrict__ x,
                                                   const float* __restrict__ subp,
                                                   const float* __restrict__ Wm,
                                                   const float* __restrict__ bias,
                                                   float* __restrict__ out,
                                                   float* __restrict__ ws) {
  __shared__ float dsel_l[4][NS];
  const int tid = threadIdx.x;
  const int w = tid >> 6, lane = tid & 63;
  const int b = blockIdx.x * 4 + w;
  const int g = ((const int*)ws)[WS_IDX + b];
  const float ss = ws[WS_SS + b];
  const float* sp2 = ws + WS_SP2 + g * NS;
  unsigned* submin = (unsigned*)ws + WS_SUBMIN;

  const int s_lo = lane >> 3, c = lane & 7;
  const float4* xv = (const float4*)(x + (size_t)b * NL) + c * 16;
  const float4* sv = (const float4*)(subp + (size_t)g * NS * NL);

  float mymin = 1e30f;
#pragma unroll
  for (int r = 0; r < 4; ++r) {
    const int s = r * 8 + s_lo;
    const float4* srow = sv + s * (NL / 4) + c * 16;
    float d = 0;
#pragma unroll
    for (int j = 0; j < 16; ++j) d += dot4(xv[j], srow[j]);
    d += __shfl_xor(d, 1, 64);
    d += __shfl_xor(d, 2, 64);
    d += __shfl_xor(d, 4, 64);
    float dv = ss + sp2[s] - 2.f * d;   // every lane of the s-group has it
    mymin = fminf(mymin, dv);
    if (c == 0) {
      dsel_l[w][s] = dv;
      atomicMin(&submin[g * NS + s], encf(dv));
    }
  }
  mymin = fminf(mymin, __shfl_xor(mymin, 8, 64));
  mymin = fminf(mymin, __shfl_xor(mymin, 16, 64));
  mymin = fminf(mymin, __shfl_xor(mymin, 32, 64));
  if (lane == 0) {
    atomicAdd(&ws[WS_GRPSUM + g], mymin);
    atomicAdd((unsigned*)ws + WS_COUNT + g, 1u);
  }
  __syncthreads();

  // expert GEMV: out[b][o] = bias + sum_s dsel[s]*W[g][o][s]
  const float* ds = dsel_l[w];
  const float4* wv = (const float4*)(Wm + (size_t)g * NO * NS);
#pragma unroll
  for (int rr = 0; rr < 4; ++rr) {
    int o = rr * 64 + lane;
    if (o < NO) {
      float a = bias[g * NO + o];
#pragma unroll
      for (int k = 0; k < 8; ++k) {
        float4 w4 = wv[o * 8 + k];
        a += ds[4 * k] * w4.x + ds[4 * k + 1] * w4.y + ds[4 * k + 2] * w4.z +
             ds[4 * k + 3] * w4.w;
      }
      out[(size_t)b * NO + o] = a;
    }
  }
}

__global__ void hier_final(const float* __restrict__ ws, float* __restrict__ out4) {
  const int lane = threadIdx.x;  // 64 threads, 1 wave
  const unsigned* colmin = (const unsigned*)ws + WS_COLMIN;
  const unsigned* submin = (const unsigned*)ws + WS_SUBMIN;
  const float* grp_sum = ws + WS_GRPSUM;
  const unsigned* counts = (const unsigned*)ws + WS_COUNT;

  float min2 = wred(decf(colmin[lane])) * (1.0f / NP);

  unsigned cnt = counts[lane];
  float s32 = 0.f;
#pragma unroll
  for (int s = 0; s < NS; s++) s32 += decf(submin[lane * NS + s]);
  float sub1 = wred((cnt > 0u) ? s32 * (1.0f / NS) : 0.f) * (1.0f / NP);
  float sub2 = wred((cnt > 0u) ? grp_sum[lane] / (float)cnt : 0.f) * (1.0f / NP);

  if (lane == 0) {
    out4[0] = ws[WS_SUM] * (1.0f / NB);
    out4[1] = min2;
    out4[2] = sub1;
    out4[3] = sub2;
  }
}

extern "C" void kernel_launch(void* const* d_in, const int* in_sizes, int n_in,
                              void* d_out, int out_size, void* d_ws, size_t ws_size,
                              hipStream_t stream) {
  const float* x = (const float*)d_in[0];
  const float* proto = (const float*)d_in[1];
  const float* subp = (const float*)d_in[2];
  const float* Wm = (const float*)d_in[3];
  const float* bias = (const float*)d_in[4];
  float* outf = (float*)d_out;
  float* ws = (float*)d_ws;

  hipLaunchKernelGGL(hier_prep, dim3(513), dim3(256), 0, stream, subp, ws);
  hipLaunchKernelGGL(hier_phase1, dim3(256), dim3(256), 0, stream, x, proto, ws);
  hipLaunchKernelGGL(hier_phase2, dim3(2048), dim3(256), 0, stream,
                     x, subp, Wm, bias, outf + 4, ws);
  hipLaunchKernelGGL(hier_final, dim3(1), dim3(64), 0, stream, ws, outf);
}